// Round 8
// baseline (1617.108 us; speedup 1.0000x reference)
//
#include <hip/hip_runtime.h>

#define B_SZ     32
#define IN_DIM   1024
#define K_TOTAL  525824          // 1024 linear + 524800 triu
#define OUT_DIM  512
#define BK       256
#define NCHUNK   2054            // K_TOTAL / BK exactly
#define KG       8
#define NEED_WS  ((size_t)B_SZ * K_TOTAL * sizeof(float))   // 67.3 MB

// async global->LDS, 16B per lane; LDS dest = wave-uniform base + lane*16
#define GLD16(g, l) __builtin_amdgcn_global_load_lds(                      \
    (const __attribute__((address_space(1))) void*)(g),                    \
    (__attribute__((address_space(3))) void*)(l), 16, 0, 0)

#define CLAMPC(c) ((c) < NCHUNK ? (c) : 0)

// ---------------------------------------------------------------- bias init
__global__ void bias_init_kernel(const float* __restrict__ bias, float* __restrict__ out)
{
    int i = blockIdx.x * 256 + threadIdx.x;     // 16384 total
    out[i] = bias[i & (OUT_DIM - 1)];
}

// ------------------------------------------------- kernel A: feature expand
__global__ __launch_bounds__(256)
void feat_kernel(const float* __restrict__ x, float* __restrict__ f)
{
    const int r   = blockIdx.x;
    const int tid = threadIdx.x;

    if (r == IN_DIM) {
        for (int b = 0; b < B_SZ; ++b)
            for (int k = tid; k < IN_DIM; k += 256)
                f[(size_t)b * K_TOTAL + k] = x[b * IN_DIM + k];
        return;
    }

    const int len = IN_DIM - r;
    const size_t base = (size_t)IN_DIM + (size_t)r * IN_DIM - (((size_t)r * (r - 1)) >> 1);
    for (int b = 0; b < B_SZ; ++b) {
        const float  xr   = x[b * IN_DIM + r];
        const float* xrow = x + b * IN_DIM + r;
        float*       frow = f + (size_t)b * K_TOTAL + base;
        for (int j = tid; j < len; j += 256)
            frow[j] = xr * xrow[j];
    }
}

// ---- kernel B: counted-vmcnt pipelined GEMM (T4), depth-2 prefetch.
// block tile 16b x 16o; 8 waves = 2 bgrp(8b) x 4 ogrp(4o); lanes span k.
// 3 f LDS buffers (48 KB) + 3 W register sets; 2 blocks/CU.
__global__ __launch_bounds__(512, 4)            // cap 128 VGPR
void qgemm_kernel(const float* __restrict__ f,
                  const float* __restrict__ W,
                  float* __restrict__ out)
{
    __shared__ float fbuf[3][16][BK];            // 48 KB, rotation distance 3

    const int tid  = threadIdx.x;
    const int lane = tid & 63;
    const int wv_  = tid >> 6;                   // wave 0..7
    const int bgrp = wv_ & 1;                    // 8 batches each
    const int ogrp = wv_ >> 1;                   // 0..3, 4 outputs each

    const int og = blockIdx.x >> 4;              // 0..31
    const int bg = (blockIdx.x >> 3) & 1;        // 0..1
    const int kg = blockIdx.x & 7;               // 0..7 (co-XCD f sharing)

    const int o_base = og * 16 + ogrp * 4;
    const int b_loc  = bgrp * 8;
    const int b_glob = bg * 16 + b_loc;
    const int col    = lane << 2;                // float index in chunk

    const float* wrow = W + (size_t)o_base * K_TOTAL + col;
    const float* frow = f + (size_t)(bg * 16) * K_TOTAL + col;

    float acc[8][4];
    #pragma unroll
    for (int i = 0; i < 8; ++i)
        #pragma unroll
        for (int j = 0; j < 4; ++j) acc[i][j] = 0.f;

    float4 ws0[4], ws1[4], ws2[4];

    // issue 2 f-GLD16 for chunk c into fbuf[s]
    #define STAGE(s, c)                                                         \
    do {                                                                        \
        const size_t kof = (size_t)CLAMPC(c) * BK;                              \
        _Pragma("unroll")                                                       \
        for (int j_ = 0; j_ < 2; ++j_) {                                        \
            const int row_ = wv_ + j_ * 8;                                      \
            GLD16(frow + (size_t)row_ * K_TOTAL + kof, &fbuf[s][row_][0]);      \
        }                                                                       \
    } while (0)

    // issue 4 W float4 loads for chunk c into register set dst
    #define WLOAD(dst, c)                                                       \
    do {                                                                        \
        const size_t kof = (size_t)CLAMPC(c) * BK;                              \
        _Pragma("unroll")                                                       \
        for (int j_ = 0; j_ < 4; ++j_)                                          \
            dst[j_] = *(const float4*)(wrow + (size_t)j_ * K_TOTAL + kof);      \
    } while (0)

    #define COMPUTE(s, ws)                                                      \
    do {                                                                        \
        _Pragma("unroll")                                                       \
        for (int i_ = 0; i_ < 8; ++i_) {                                        \
            const float4 fv = *(const float4*)&fbuf[s][b_loc + i_][col];        \
            _Pragma("unroll")                                                   \
            for (int j_ = 0; j_ < 4; ++j_)                                      \
                acc[i_][j_] += fv.x * ws[j_].x + fv.y * ws[j_].y                \
                             + fv.z * ws[j_].z + fv.w * ws[j_].w;               \
        }                                                                       \
    } while (0)

    // one pipelined iteration: compute chunk c from {bufc, wcur};
    // prefetch W(c+16)->wpre2, f(c+8)->bufn; wait leaves newest 6 in flight.
    #define SUB(bufc, bufn, wcur, wpre2)                                        \
    do {                                                                        \
        WLOAD(wpre2, c + 16);                                                   \
        STAGE(bufn, c + 8);                                                     \
        __builtin_amdgcn_sched_barrier(0);                                      \
        asm volatile("s_waitcnt vmcnt(6)" ::: "memory");                        \
        __builtin_amdgcn_sched_barrier(0);                                      \
        __builtin_amdgcn_s_barrier();                                           \
        COMPUTE(bufc, wcur);                                                    \
        c += KG;                                                                \
    } while (0)

    int c = kg;
    // prologue: W(c0)->ws0, f(c0)->buf0, W(c1)->ws1   (10 vmem in flight)
    WLOAD(ws0, c);
    STAGE(0, c);
    WLOAD(ws1, c + 8);

    // main: i = 0..254 (255 = 85*3 iterations), all issues valid or clamped
    for (int it = 0; it < 85; ++it) {
        SUB(0, 1, ws0, ws2);
        SUB(1, 2, ws1, ws0);
        SUB(2, 0, ws2, ws1);
    }

    // epilogue i=255: c = kg+2040 (always valid); stage f(c+8) clamped
    STAGE(1, c + 8);
    __builtin_amdgcn_sched_barrier(0);
    asm volatile("s_waitcnt vmcnt(2)" ::: "memory");
    __builtin_amdgcn_sched_barrier(0);
    __builtin_amdgcn_s_barrier();
    COMPUTE(0, ws0);
    c += KG;

    // epilogue i=256: c = kg+2048, valid only for kg<6
    asm volatile("s_waitcnt vmcnt(0)" ::: "memory");
    __builtin_amdgcn_sched_barrier(0);
    __builtin_amdgcn_s_barrier();
    if (c < NCHUNK)
        COMPUTE(1, ws1);

    #undef SUB
    #undef COMPUTE
    #undef WLOAD
    #undef STAGE

    // butterfly-reduce each acc element over the 64 k-lanes
    #pragma unroll
    for (int i = 0; i < 8; ++i)
        #pragma unroll
        for (int j = 0; j < 4; ++j) {
            float v = acc[i][j];
            #pragma unroll
            for (int m = 1; m < 64; m <<= 1)
                v += __shfl_xor(v, m);
            acc[i][j] = v;
        }

    if (lane == 0) {
        #pragma unroll
        for (int i = 0; i < 8; ++i)
            #pragma unroll
            for (int j = 0; j < 4; ++j)
                atomicAdd(&out[(b_glob + i) * OUT_DIM + o_base + j], acc[i][j]);
    }
}

// ------------------------------------------------- fallback (proven v2 path)
__global__ __launch_bounds__(512, 2)
void qgemm_fallback_kernel(const float* __restrict__ x,
                           const float* __restrict__ W,
                           float* __restrict__ out)
{
    __shared__ float xt[B_SZ][512];

    const int tid  = threadIdx.x;
    const int lane = tid & 63;
    const int wave = tid >> 6;
    const int bgrp = wave & 3;
    const int ogrp = wave >> 2;

    const int og  = blockIdx.x & 31;
    const int kgf = blockIdx.x >> 5;

    const int o_base = og * 16 + ogrp * 8;
    const int b_base = bgrp * 8;

    float acc[8][8];
    #pragma unroll
    for (int i = 0; i < 8; ++i)
        #pragma unroll
        for (int o = 0; o < 8; ++o) acc[i][o] = 0.f;

    const int nch = (K_TOTAL + 511) / 512;
    for (int chunk = kgf; chunk < nch; chunk += 16) {
        const int k = chunk * 512 + tid;
        __syncthreads();
        if (k < IN_DIM) {
            #pragma unroll
            for (int b = 0; b < B_SZ; ++b)
                xt[b][tid] = x[b * IN_DIM + k];
        } else {
            const int t = k - IN_DIM;
            double disc = 4198401.0 - 8.0 * (double)t;
            int r = (int)((2049.0 - sqrt(disc)) * 0.5);
            int off = r * IN_DIM - ((r * (r - 1)) >> 1);
            if (t < off) { --r; off = r * IN_DIM - ((r * (r - 1)) >> 1); }
            else if (t >= off + (IN_DIM - r)) { off += IN_DIM - r; ++r; }
            const int ccol = r + (t - off);
            #pragma unroll
            for (int b = 0; b < B_SZ; ++b)
                xt[b][tid] = x[b * IN_DIM + r] * x[b * IN_DIM + ccol];
        }
        __syncthreads();

        const float* wrow = W + (size_t)o_base * K_TOTAL + (size_t)chunk * 512;
        #pragma unroll
        for (int pass = 0; pass < 2; ++pass) {
            const int kk = pass * 256 + lane * 4;
            float4 wv[8];
            #pragma unroll
            for (int o = 0; o < 8; ++o)
                wv[o] = *(const float4*)(wrow + (size_t)o * K_TOTAL + kk);
            float4 xv[8];
            #pragma unroll
            for (int i = 0; i < 8; ++i)
                xv[i] = *(const float4*)&xt[b_base + i][kk];
            #pragma unroll
            for (int o = 0; o < 8; ++o)
                #pragma unroll
                for (int i = 0; i < 8; ++i)
                    acc[i][o] += xv[i].x * wv[o].x + xv[i].y * wv[o].y
                               + xv[i].z * wv[o].z + xv[i].w * wv[o].w;
        }
    }

    #pragma unroll
    for (int i = 0; i < 8; ++i)
        #pragma unroll
        for (int o = 0; o < 8; ++o) {
            float v = acc[i][o];
            #pragma unroll
            for (int m = 1; m < 64; m <<= 1)
                v += __shfl_xor(v, m);
            acc[i][o] = v;
        }

    if (lane == 0) {
        #pragma unroll
        for (int i = 0; i < 8; ++i)
            #pragma unroll
            for (int o = 0; o < 8; ++o)
                atomicAdd(&out[(b_base + i) * OUT_DIM + o_base + o], acc[i][o]);
    }
}

extern "C" void kernel_launch(void* const* d_in, const int* in_sizes, int n_in,
                              void* d_out, int out_size, void* d_ws, size_t ws_size,
                              hipStream_t stream)
{
    const float* x    = (const float*)d_in[0];   // [32,1024] fp32
    const float* W    = (const float*)d_in[1];   // [512, 525824] fp32
    const float* bias = (const float*)d_in[2];   // [512] fp32
    float* out = (float*)d_out;                  // [32,512] fp32

    hipLaunchKernelGGL(bias_init_kernel, dim3(64), dim3(256), 0, stream, bias, out);

    if (ws_size >= NEED_WS) {
        float* f = (float*)d_ws;
        hipLaunchKernelGGL(feat_kernel, dim3(IN_DIM + 1), dim3(256), 0, stream, x, f);
        hipLaunchKernelGGL(qgemm_kernel, dim3(512), dim3(512), 0, stream, f, W, out);
    } else {
        hipLaunchKernelGGL(qgemm_fallback_kernel, dim3(512), dim3(512), 0, stream,
                           x, W, out);
    }
}

// Round 9
// 600.934 us; speedup vs baseline: 2.6910x; 2.6910x over previous
//
#include <hip/hip_runtime.h>

#define B_SZ     32
#define IN_DIM   1024
#define K_TOTAL  525824          // 1024 linear + 524800 triu
#define OUT_DIM  512
#define BK       256
#define NCHUNK   2054            // K_TOTAL / BK exactly
#define KG       8
#define NEED_WS  ((size_t)B_SZ * K_TOTAL * sizeof(float))   // 67.3 MB

// async global->LDS, 16B per lane; LDS dest = wave-uniform base + lane*16
#define GLD16(g, l) __builtin_amdgcn_global_load_lds(                      \
    (const __attribute__((address_space(1))) void*)(g),                    \
    (__attribute__((address_space(3))) void*)(l), 16, 0, 0)

// ---------------------------------------------------------------- bias init
__global__ void bias_init_kernel(const float* __restrict__ bias, float* __restrict__ out)
{
    int i = blockIdx.x * 256 + threadIdx.x;     // 16384 total
    out[i] = bias[i & (OUT_DIM - 1)];
}

// ------------------------------------------------- kernel A: feature expand
__global__ __launch_bounds__(256)
void feat_kernel(const float* __restrict__ x, float* __restrict__ f)
{
    const int r   = blockIdx.x;
    const int tid = threadIdx.x;

    if (r == IN_DIM) {
        for (int b = 0; b < B_SZ; ++b)
            for (int k = tid; k < IN_DIM; k += 256)
                f[(size_t)b * K_TOTAL + k] = x[b * IN_DIM + k];
        return;
    }

    const int len = IN_DIM - r;
    const size_t base = (size_t)IN_DIM + (size_t)r * IN_DIM - (((size_t)r * (r - 1)) >> 1);
    for (int b = 0; b < B_SZ; ++b) {
        const float  xr   = x[b * IN_DIM + r];
        const float* xrow = x + b * IN_DIM + r;
        float*       frow = f + (size_t)b * K_TOTAL + base;
        for (int j = tid; j < len; j += 256)
            frow[j] = xr * xrow[j];
    }
}

// ---- kernel B: all-LDS double-buffered GEMM, affine 255-iter main loop.
// tile 32b x 16o per block; 8 waves = 4 bgrp(8b) x 2 ogrp(8o); lanes span k.
// f and W both staged via global_load_lds: no prefetch VGPR state at all.
__global__ __launch_bounds__(512, 2)
void qgemm_kernel(const float* __restrict__ f,
                  const float* __restrict__ W,
                  float* __restrict__ out)
{
    __shared__ float fbuf[2][B_SZ][BK];          // 64 KB
    __shared__ float wbuf[2][16][BK];            // 32 KB

    const int tid  = threadIdx.x;
    const int lane = tid & 63;
    const int wv_  = tid >> 6;                   // wave 0..7
    const int bgrp = wv_ & 3;                    // 8 batches each
    const int ogrp = wv_ >> 2;                   // 0..1, 8 outputs each

    const int og = blockIdx.x >> 3;              // 0..31
    const int kg = blockIdx.x & 7;               // 0..7 (f-sharing blocks co-XCD)

    const int o_base = og * 16;
    const int o_w    = ogrp * 8;
    const int b_base = bgrp * 8;
    const int col    = lane << 2;                // float index in chunk

    const float* fsrc = f + col;                 // + row*K_TOTAL + chunk*BK
    const float* wsrc = W + (size_t)o_base * K_TOTAL + col;

    float acc[8][8];
    #pragma unroll
    for (int i = 0; i < 8; ++i)
        #pragma unroll
        for (int o = 0; o < 8; ++o) acc[i][o] = 0.f;

    // stage chunk c into buffer s: 4 f-rows + 2 W-rows per wave, all GLD16
    #define STAGE(s, c)                                                         \
    do {                                                                        \
        const size_t kof = (size_t)(c) * BK;                                    \
        _Pragma("unroll")                                                       \
        for (int j_ = 0; j_ < 4; ++j_) {                                        \
            const int row_ = wv_ + j_ * 8;       /* 0..31 */                    \
            GLD16(fsrc + (size_t)row_ * K_TOTAL + kof, &fbuf[s][row_][0]);      \
        }                                                                       \
        _Pragma("unroll")                                                       \
        for (int j_ = 0; j_ < 2; ++j_) {                                        \
            const int row_ = wv_ + j_ * 8;       /* 0..15 */                    \
            GLD16(wsrc + (size_t)row_ * K_TOTAL + kof, &wbuf[s][row_][0]);      \
        }                                                                       \
    } while (0)

    #define COMPUTE(s)                                                          \
    do {                                                                        \
        float4 wvv[8];                                                          \
        _Pragma("unroll")                                                       \
        for (int o_ = 0; o_ < 8; ++o_)                                          \
            wvv[o_] = *(const float4*)&wbuf[s][o_w + o_][col];                  \
        _Pragma("unroll")                                                       \
        for (int i_ = 0; i_ < 8; ++i_) {                                        \
            const float4 fv = *(const float4*)&fbuf[s][b_base + i_][col];       \
            _Pragma("unroll")                                                   \
            for (int o_ = 0; o_ < 8; ++o_)                                      \
                acc[i_][o_] += fv.x * wvv[o_].x + fv.y * wvv[o_].y              \
                             + fv.z * wvv[o_].z + fv.w * wvv[o_].w;             \
        }                                                                       \
    } while (0)

    int c = kg;                                  // chunk = kg + 8t
    STAGE(0, c);
    __syncthreads();

    // main loop: 255 affine iterations, no conditionals, no clamps
    for (int t = 0; t < 255; ++t) {
        const int s = t & 1;
        STAGE(s ^ 1, c + KG);                    // prefetch issued at top
        COMPUTE(s);                              // ~1100 cy: covers HBM latency
        __syncthreads();                         // vmcnt(0)+barrier
        c += KG;
    }

    // peeled iteration 255: c = kg+2040 (valid for all kg), data in buf1
    {
        const bool tail = (kg < 6);              // chunk kg+2048 exists iff kg<6
        STAGE(0, tail ? c + KG : c);             // uniform select; re-stage harmless
        COMPUTE(1);
        __syncthreads();
        if (tail) COMPUTE(0);
    }
    #undef COMPUTE
    #undef STAGE

    // butterfly-reduce each acc element over the 64 k-lanes
    #pragma unroll
    for (int i = 0; i < 8; ++i)
        #pragma unroll
        for (int o = 0; o < 8; ++o) {
            float v = acc[i][o];
            #pragma unroll
            for (int m = 1; m < 64; m <<= 1)
                v += __shfl_xor(v, m);
            acc[i][o] = v;
        }

    if (lane == 0) {
        #pragma unroll
        for (int i = 0; i < 8; ++i)
            #pragma unroll
            for (int o = 0; o < 8; ++o)
                atomicAdd(&out[(b_base + i) * OUT_DIM + o_base + o_w + o], acc[i][o]);
    }
}

// ------------------------------------------------- fallback (proven v2 path)
__global__ __launch_bounds__(512, 2)
void qgemm_fallback_kernel(const float* __restrict__ x,
                           const float* __restrict__ W,
                           float* __restrict__ out)
{
    __shared__ float xt[B_SZ][512];

    const int tid  = threadIdx.x;
    const int lane = tid & 63;
    const int wave = tid >> 6;
    const int bgrp = wave & 3;
    const int ogrp = wave >> 2;

    const int og  = blockIdx.x & 31;
    const int kgf = blockIdx.x >> 5;

    const int o_base = og * 16 + ogrp * 8;
    const int b_base = bgrp * 8;

    float acc[8][8];
    #pragma unroll
    for (int i = 0; i < 8; ++i)
        #pragma unroll
        for (int o = 0; o < 8; ++o) acc[i][o] = 0.f;

    const int nch = (K_TOTAL + 511) / 512;
    for (int chunk = kgf; chunk < nch; chunk += 16) {
        const int k = chunk * 512 + tid;
        __syncthreads();
        if (k < IN_DIM) {
            #pragma unroll
            for (int b = 0; b < B_SZ; ++b)
                xt[b][tid] = x[b * IN_DIM + k];
        } else {
            const int t = k - IN_DIM;
            double disc = 4198401.0 - 8.0 * (double)t;
            int r = (int)((2049.0 - sqrt(disc)) * 0.5);
            int off = r * IN_DIM - ((r * (r - 1)) >> 1);
            if (t < off) { --r; off = r * IN_DIM - ((r * (r - 1)) >> 1); }
            else if (t >= off + (IN_DIM - r)) { off += IN_DIM - r; ++r; }
            const int ccol = r + (t - off);
            #pragma unroll
            for (int b = 0; b < B_SZ; ++b)
                xt[b][tid] = x[b * IN_DIM + r] * x[b * IN_DIM + ccol];
        }
        __syncthreads();

        const float* wrow = W + (size_t)o_base * K_TOTAL + (size_t)chunk * 512;
        #pragma unroll
        for (int pass = 0; pass < 2; ++pass) {
            const int kk = pass * 256 + lane * 4;
            float4 wv[8];
            #pragma unroll
            for (int o = 0; o < 8; ++o)
                wv[o] = *(const float4*)(wrow + (size_t)o * K_TOTAL + kk);
            float4 xv[8];
            #pragma unroll
            for (int i = 0; i < 8; ++i)
                xv[i] = *(const float4*)&xt[b_base + i][kk];
            #pragma unroll
            for (int o = 0; o < 8; ++o)
                #pragma unroll
                for (int i = 0; i < 8; ++i)
                    acc[i][o] += xv[i].x * wv[o].x + xv[i].y * wv[o].y
                               + xv[i].z * wv[o].z + xv[i].w * wv[o].w;
        }
    }

    #pragma unroll
    for (int i = 0; i < 8; ++i)
        #pragma unroll
        for (int o = 0; o < 8; ++o) {
            float v = acc[i][o];
            #pragma unroll
            for (int m = 1; m < 64; m <<= 1)
                v += __shfl_xor(v, m);
            acc[i][o] = v;
        }

    if (lane == 0) {
        #pragma unroll
        for (int i = 0; i < 8; ++i)
            #pragma unroll
            for (int o = 0; o < 8; ++o)
                atomicAdd(&out[(b_base + i) * OUT_DIM + o_base + o], acc[i][o]);
    }
}

extern "C" void kernel_launch(void* const* d_in, const int* in_sizes, int n_in,
                              void* d_out, int out_size, void* d_ws, size_t ws_size,
                              hipStream_t stream)
{
    const float* x    = (const float*)d_in[0];   // [32,1024] fp32
    const float* W    = (const float*)d_in[1];   // [512, 525824] fp32
    const float* bias = (const float*)d_in[2];   // [512] fp32
    float* out = (float*)d_out;                  // [32,512] fp32

    hipLaunchKernelGGL(bias_init_kernel, dim3(64), dim3(256), 0, stream, bias, out);

    if (ws_size >= NEED_WS) {
        float* f = (float*)d_ws;
        hipLaunchKernelGGL(feat_kernel, dim3(IN_DIM + 1), dim3(256), 0, stream, x, f);
        hipLaunchKernelGGL(qgemm_kernel, dim3(256), dim3(512), 0, stream, f, W, out);
    } else {
        hipLaunchKernelGGL(qgemm_fallback_kernel, dim3(512), dim3(512), 0, stream,
                           x, W, out);
    }
}

// Round 10
// 517.774 us; speedup vs baseline: 3.1232x; 1.1606x over previous
//
#include <hip/hip_runtime.h>

#define B_SZ     32
#define IN_DIM   1024
#define K_TOTAL  525824          // 1024 linear + 524800 triu
#define OUT_DIM  512
#define BK       256
#define NCHUNK   2054            // K_TOTAL / BK exactly
#define KG       8
#define NEED_WS  ((size_t)B_SZ * K_TOTAL * sizeof(float))   // 67.3 MB

// async global->LDS, 16B per lane; LDS dest = wave-uniform base + lane*16
#define GLD16(g, l) __builtin_amdgcn_global_load_lds(                      \
    (const __attribute__((address_space(1))) void*)(g),                    \
    (__attribute__((address_space(3))) void*)(l), 16, 0, 0)

// ---------------------------------------------------------------- bias init
__global__ void bias_init_kernel(const float* __restrict__ bias, float* __restrict__ out)
{
    int i = blockIdx.x * 256 + threadIdx.x;     // 16384 total
    out[i] = bias[i & (OUT_DIM - 1)];
}

// ------------------------------------------------- kernel A: feature expand
__global__ __launch_bounds__(256)
void feat_kernel(const float* __restrict__ x, float* __restrict__ f)
{
    const int r   = blockIdx.x;
    const int tid = threadIdx.x;

    if (r == IN_DIM) {
        for (int b = 0; b < B_SZ; ++b)
            for (int k = tid; k < IN_DIM; k += 256)
                f[(size_t)b * K_TOTAL + k] = x[b * IN_DIM + k];
        return;
    }

    const int len = IN_DIM - r;
    const size_t base = (size_t)IN_DIM + (size_t)r * IN_DIM - (((size_t)r * (r - 1)) >> 1);
    for (int b = 0; b < B_SZ; ++b) {
        const float  xr   = x[b * IN_DIM + r];
        const float* xrow = x + b * IN_DIM + r;
        float*       frow = f + (size_t)b * K_TOTAL + base;
        for (int j = tid; j < len; j += 256)
            frow[j] = xr * xrow[j];
    }
}

// ---- kernel B: 3-deep counted-vmcnt pipeline, all staging via global_load_lds.
// tile 32b x 16o per block; 8 waves = 4 bgrp(8b) x 2 ogrp(8o); lanes span k.
// Per iter: vmcnt(6) -> s_barrier -> STAGE(t+2) -> COMPUTE(t). Stages for t+1,
// t+2 (12 vmem ops/wave) stay in flight across the barrier; no vmcnt(0) drain.
__global__ __launch_bounds__(512, 2)
void qgemm_kernel(const float* __restrict__ f,
                  const float* __restrict__ W,
                  float* __restrict__ out)
{
    __shared__ float fbuf[3][B_SZ][BK];          // 96 KB
    __shared__ float wbuf[3][16][BK];            // 48 KB   (144 KB total, 1 blk/CU)

    const int tid  = threadIdx.x;
    const int lane = tid & 63;
    const int wv_  = tid >> 6;                   // wave 0..7
    const int bgrp = wv_ & 3;                    // 8 batches each
    const int ogrp = wv_ >> 2;                   // 0..1, 8 outputs each

    const int og = blockIdx.x >> 3;              // 0..31
    const int kg = blockIdx.x & 7;               // 0..7 (f-sharing blocks co-XCD)

    const int o_base = og * 16;
    const int o_w    = ogrp * 8;
    const int b_base = bgrp * 8;
    const int col    = lane << 2;                // float index in chunk

    const float* fsrc = f + col;
    const float* wsrc = W + (size_t)o_base * K_TOTAL + col;

    float acc[8][8];
    #pragma unroll
    for (int i = 0; i < 8; ++i)
        #pragma unroll
        for (int o = 0; o < 8; ++o) acc[i][o] = 0.f;

    // stage chunk c into buffer s: 4 f-rows + 2 W-rows per wave, all GLD16
    #define STAGE(s, c)                                                         \
    do {                                                                        \
        const size_t kof = (size_t)(c) * BK;                                    \
        _Pragma("unroll")                                                       \
        for (int j_ = 0; j_ < 4; ++j_) {                                        \
            const int row_ = wv_ + j_ * 8;       /* 0..31 */                    \
            GLD16(fsrc + (size_t)row_ * K_TOTAL + kof, &fbuf[s][row_][0]);      \
        }                                                                       \
        _Pragma("unroll")                                                       \
        for (int j_ = 0; j_ < 2; ++j_) {                                        \
            const int row_ = wv_ + j_ * 8;       /* 0..15 */                    \
            GLD16(wsrc + (size_t)row_ * K_TOTAL + kof, &wbuf[s][row_][0]);      \
        }                                                                       \
    } while (0)

    #define COMPUTE(s)                                                          \
    do {                                                                        \
        float4 wvv[8];                                                          \
        _Pragma("unroll")                                                       \
        for (int o_ = 0; o_ < 8; ++o_)                                          \
            wvv[o_] = *(const float4*)&wbuf[s][o_w + o_][col];                  \
        _Pragma("unroll")                                                       \
        for (int i_ = 0; i_ < 8; ++i_) {                                        \
            const float4 fv = *(const float4*)&fbuf[s][b_base + i_][col];       \
            _Pragma("unroll")                                                   \
            for (int o_ = 0; o_ < 8; ++o_)                                      \
                acc[i_][o_] += fv.x * wvv[o_].x + fv.y * wvv[o_].y              \
                             + fv.z * wvv[o_].z + fv.w * wvv[o_].w;             \
        }                                                                       \
    } while (0)

    // chunks this block owns: kg, kg+8, ... ; count NC = 257 (kg<6) else 256
    const int NC = (kg < 6) ? 257 : 256;

    STAGE(0, kg);                                // stage(0)
    STAGE(1, kg + KG);                           // stage(1): 12 ops in flight

    int sA = 0;                                  // buffer to compute
    int sS = 2;                                  // buffer to stage (= sA+2 mod 3)
    int cs = kg + 2 * KG;                        // chunk to stage

    for (int t = 0; t < NC - 2; ++t) {
        asm volatile("s_waitcnt vmcnt(6)" ::: "memory");  // stage(t) landed
        __builtin_amdgcn_s_barrier();            // all waves past COMPUTE(t-1)
        STAGE(sS, cs);                           // overwrite buffer of t-1
        __builtin_amdgcn_sched_barrier(0);       // pin issue-early
        COMPUTE(sA);
        sA = (sA == 2) ? 0 : sA + 1;
        sS = (sS == 2) ? 0 : sS + 1;
        cs += KG;
    }

    // t = NC-2: stage(NC-2) done after draining to 6 (only stage(NC-1) left)
    asm volatile("s_waitcnt vmcnt(6)" ::: "memory");
    __builtin_amdgcn_s_barrier();
    COMPUTE(sA);
    sA = (sA == 2) ? 0 : sA + 1;

    // t = NC-1: final drain
    asm volatile("s_waitcnt vmcnt(0)" ::: "memory");
    __builtin_amdgcn_s_barrier();
    COMPUTE(sA);

    #undef COMPUTE
    #undef STAGE

    // butterfly-reduce each acc element over the 64 k-lanes
    #pragma unroll
    for (int i = 0; i < 8; ++i)
        #pragma unroll
        for (int o = 0; o < 8; ++o) {
            float v = acc[i][o];
            #pragma unroll
            for (int m = 1; m < 64; m <<= 1)
                v += __shfl_xor(v, m);
            acc[i][o] = v;
        }

    if (lane == 0) {
        #pragma unroll
        for (int i = 0; i < 8; ++i)
            #pragma unroll
            for (int o = 0; o < 8; ++o)
                atomicAdd(&out[(b_base + i) * OUT_DIM + o_base + o_w + o], acc[i][o]);
    }
}

// ------------------------------------------------- fallback (proven v2 path)
__global__ __launch_bounds__(512, 2)
void qgemm_fallback_kernel(const float* __restrict__ x,
                           const float* __restrict__ W,
                           float* __restrict__ out)
{
    __shared__ float xt[B_SZ][512];

    const int tid  = threadIdx.x;
    const int lane = tid & 63;
    const int wave = tid >> 6;
    const int bgrp = wave & 3;
    const int ogrp = wave >> 2;

    const int og  = blockIdx.x & 31;
    const int kgf = blockIdx.x >> 5;

    const int o_base = og * 16 + ogrp * 8;
    const int b_base = bgrp * 8;

    float acc[8][8];
    #pragma unroll
    for (int i = 0; i < 8; ++i)
        #pragma unroll
        for (int o = 0; o < 8; ++o) acc[i][o] = 0.f;

    const int nch = (K_TOTAL + 511) / 512;
    for (int chunk = kgf; chunk < nch; chunk += 16) {
        const int k = chunk * 512 + tid;
        __syncthreads();
        if (k < IN_DIM) {
            #pragma unroll
            for (int b = 0; b < B_SZ; ++b)
                xt[b][tid] = x[b * IN_DIM + k];
        } else {
            const int t = k - IN_DIM;
            double disc = 4198401.0 - 8.0 * (double)t;
            int r = (int)((2049.0 - sqrt(disc)) * 0.5);
            int off = r * IN_DIM - ((r * (r - 1)) >> 1);
            if (t < off) { --r; off = r * IN_DIM - ((r * (r - 1)) >> 1); }
            else if (t >= off + (IN_DIM - r)) { off += IN_DIM - r; ++r; }
            const int ccol = r + (t - off);
            #pragma unroll
            for (int b = 0; b < B_SZ; ++b)
                xt[b][tid] = x[b * IN_DIM + r] * x[b * IN_DIM + ccol];
        }
        __syncthreads();

        const float* wrow = W + (size_t)o_base * K_TOTAL + (size_t)chunk * 512;
        #pragma unroll
        for (int pass = 0; pass < 2; ++pass) {
            const int kk = pass * 256 + lane * 4;
            float4 wv[8];
            #pragma unroll
            for (int o = 0; o < 8; ++o)
                wv[o] = *(const float4*)(wrow + (size_t)o * K_TOTAL + kk);
            float4 xv[8];
            #pragma unroll
            for (int i = 0; i < 8; ++i)
                xv[i] = *(const float4*)&xt[b_base + i][kk];
            #pragma unroll
            for (int o = 0; o < 8; ++o)
                #pragma unroll
                for (int i = 0; i < 8; ++i)
                    acc[i][o] += xv[i].x * wv[o].x + xv[i].y * wv[o].y
                               + xv[i].z * wv[o].z + xv[i].w * wv[o].w;
        }
    }

    #pragma unroll
    for (int i = 0; i < 8; ++i)
        #pragma unroll
        for (int o = 0; o < 8; ++o) {
            float v = acc[i][o];
            #pragma unroll
            for (int m = 1; m < 64; m <<= 1)
                v += __shfl_xor(v, m);
            acc[i][o] = v;
        }

    if (lane == 0) {
        #pragma unroll
        for (int i = 0; i < 8; ++i)
            #pragma unroll
            for (int o = 0; o < 8; ++o)
                atomicAdd(&out[(b_base + i) * OUT_DIM + o_base + o], acc[i][o]);
    }
}

extern "C" void kernel_launch(void* const* d_in, const int* in_sizes, int n_in,
                              void* d_out, int out_size, void* d_ws, size_t ws_size,
                              hipStream_t stream)
{
    const float* x    = (const float*)d_in[0];   // [32,1024] fp32
    const float* W    = (const float*)d_in[1];   // [512, 525824] fp32
    const float* bias = (const float*)d_in[2];   // [512] fp32
    float* out = (float*)d_out;                  // [32,512] fp32

    hipLaunchKernelGGL(bias_init_kernel, dim3(64), dim3(256), 0, stream, bias, out);

    if (ws_size >= NEED_WS) {
        float* f = (float*)d_ws;
        hipLaunchKernelGGL(feat_kernel, dim3(IN_DIM + 1), dim3(256), 0, stream, x, f);
        hipLaunchKernelGGL(qgemm_kernel, dim3(256), dim3(512), 0, stream, f, W, out);
    } else {
        hipLaunchKernelGGL(qgemm_fallback_kernel, dim3(512), dim3(512), 0, stream,
                           x, W, out);
    }
}

// Round 12
// 309.289 us; speedup vs baseline: 5.2285x; 1.6741x over previous
//
#include <hip/hip_runtime.h>
#include <hip/hip_bf16.h>

#define B_SZ     32
#define IN_DIM   1024
#define K_TOTAL  525824          // 1024 linear + 524800 triu = 4108 * 128
#define OUT_DIM  512
#define NCH      4108            // 128-k chunks
#define KS       64              // k-segment count (chunk stride)
#define NEED_WS  ((size_t)NCH * 512 * 16)   // 33.65 MB packed bf16 features

typedef __attribute__((ext_vector_type(8))) short bfrag;   // 8 bf16 = 4 VGPR
typedef __attribute__((ext_vector_type(4))) float f32x4;

// async global->LDS, 16B per lane; LDS dest = wave-uniform base + lane*16
#define GLD16(g, l) __builtin_amdgcn_global_load_lds(                      \
    (const __attribute__((address_space(1))) void*)(g),                    \
    (__attribute__((address_space(3))) void*)(l), 16, 0, 0)

// fp32 -> bf16 with round-to-nearest-even (pure integer, trivially copyable)
__device__ inline unsigned bf16r(float f)
{
    unsigned u = __builtin_bit_cast(unsigned, f);
    return (u + 0x7FFFu + ((u >> 16) & 1u)) >> 16;
}
// pack 2 fp32 -> one u32 of 2 bf16 (lo = a, hi = b)
__device__ inline unsigned pk2(float a, float b)
{
    return bf16r(a) | (bf16r(b) << 16);
}

// ---------------------------------------------------------------- bias init
__global__ void bias_init_kernel(const float* __restrict__ bias, float* __restrict__ out)
{
    int i = blockIdx.x * 256 + threadIdx.x;     // 16384 total
    out[i] = bias[i & (OUT_DIM - 1)];
}

// ------------- kernel A: feature expand -> bf16, MFMA-A-fragment packed
// layout: unit u = (chunk*16 + koctet)*32 + b holds f[b][chunk*128+koctet*8 .. +7]
__global__ __launch_bounds__(256)
void feat_pack_kernel(const float* __restrict__ x, int4* __restrict__ fp)
{
    const int chunk = blockIdx.x;               // 0..4107
    const int tid   = threadIdx.x;

    #pragma unroll
    for (int i = 0; i < 2; ++i) {
        const int unit = tid + i * 256;         // 0..511
        const int kb   = unit >> 5;             // k-octet 0..15
        const int b    = unit & 31;
        const int k0   = chunk * 128 + kb * 8;
        const float* xb = x + b * IN_DIM;

        float v[8];
        if (chunk < 8) {                        // linear features (k < 1024)
            #pragma unroll
            for (int e = 0; e < 8; ++e) v[e] = xb[k0 + e];
        } else {                                // quadratic: walk (r,c) from one sqrt
            int t = k0 - IN_DIM;
            double disc = 4198401.0 - 8.0 * (double)t;   // 2049^2 - 8t
            int r = (int)((2049.0 - sqrt(disc)) * 0.5);
            int off = r * IN_DIM - ((r * (r - 1)) >> 1);
            if (t < off) { --r; off = r * IN_DIM - ((r * (r - 1)) >> 1); }
            else if (t >= off + (IN_DIM - r)) { off += IN_DIM - r; ++r; }
            int c_ = r + (t - off);
            #pragma unroll
            for (int e = 0; e < 8; ++e) {
                v[e] = xb[r] * xb[c_];
                if (c_ == IN_DIM - 1) { ++r; c_ = r; } else { ++c_; }
            }
        }
        int4 pk;
        pk.x = (int)pk2(v[0], v[1]);
        pk.y = (int)pk2(v[2], v[3]);
        pk.z = (int)pk2(v[4], v[5]);
        pk.w = (int)pk2(v[6], v[7]);
        fp[(size_t)chunk * 512 + unit] = pk;
    }
}

// ------------- kernel B: MFMA GEMM. Wave = one o-16-tile x one k-segment.
// A (f) bf16 from packed LDS; B (W) fp32 global->reg->cvt; C = 2x f32x4/lane.
// Block = 4 waves sharing f-LDS; 3-buf f staging, W reg-prefetch 1 chunk ahead.
__global__ __launch_bounds__(256, 2)
void qgemm_mfma_kernel(const int4* __restrict__ fp,
                       const float* __restrict__ W,
                       float* __restrict__ out)
{
    __shared__ int4 fbuf[3][512];                // 3 x 8 KB

    const int tid  = threadIdx.x;
    const int lane = tid & 63;
    const int wv_  = tid >> 6;                   // 0..3
    const int lrow = lane & 15;                  // A row / B col within tile
    const int lkb  = lane >> 4;                  // k-octet group 0..3

    const int og = blockIdx.x >> 6;              // 0..7
    const int kg = blockIdx.x & 63;              // 0..63 (co-XCD f sharing)

    const int o_base = og * 64 + wv_ * 16;
    const float* wlane = W + (size_t)(o_base + lrow) * K_TOTAL;
    const char*  fpB   = (const char*)fp + (size_t)lane * 16;

    f32x4 acc0 = {0.f, 0.f, 0.f, 0.f};
    f32x4 acc1 = {0.f, 0.f, 0.f, 0.f};
    float4 wc[8], wn[8];

    #define WLOADR(dst, cc)                                                     \
    do {                                                                        \
        const float* wp_ = wlane + (size_t)(cc) * 128 + lkb * 8;                \
        _Pragma("unroll")                                                       \
        for (int q_ = 0; q_ < 4; ++q_) {                                        \
            dst[2*q_]   = *(const float4*)(wp_ + q_ * 32);                      \
            dst[2*q_+1] = *(const float4*)(wp_ + q_ * 32 + 4);                  \
        }                                                                       \
    } while (0)

    #define STAGEF(s, cc)                                                       \
    do {                                                                        \
        const char* gp_ = fpB + (size_t)(cc) * 8192;                            \
        GLD16(gp_ + wv_ * 1024,        (char*)&fbuf[s][0] + wv_ * 1024);        \
        GLD16(gp_ + 4096 + wv_ * 1024, (char*)&fbuf[s][0] + 4096 + wv_ * 1024); \
    } while (0)

    #define COMPUTE(cbuf)                                                       \
    do {                                                                        \
        const int4* bp_ = &fbuf[cbuf][0];                                       \
        _Pragma("unroll")                                                       \
        for (int q_ = 0; q_ < 4; ++q_) {                                        \
            int4 tw_;                                                           \
            tw_.x = (int)pk2(wc[2*q_].x,   wc[2*q_].y);                         \
            tw_.y = (int)pk2(wc[2*q_].z,   wc[2*q_].w);                         \
            tw_.z = (int)pk2(wc[2*q_+1].x, wc[2*q_+1].y);                       \
            tw_.w = (int)pk2(wc[2*q_+1].z, wc[2*q_+1].w);                       \
            const bfrag bw_ = __builtin_bit_cast(bfrag, tw_);                   \
            const int ub_ = (q_ * 4 + lkb) * 32 + lrow;                         \
            const bfrag a0_ = __builtin_bit_cast(bfrag, bp_[ub_]);              \
            const bfrag a1_ = __builtin_bit_cast(bfrag, bp_[ub_ + 16]);         \
            acc0 = __builtin_amdgcn_mfma_f32_16x16x32_bf16(a0_, bw_, acc0, 0, 0, 0); \
            acc1 = __builtin_amdgcn_mfma_f32_16x16x32_bf16(a1_, bw_, acc1, 0, 0, 0); \
        }                                                                       \
    } while (0)

    int c = kg;
    STAGEF(0, c);                                // f(c)         [f x2]
    WLOADR(wn, c);                               // W(c)         [f2 W8]
    STAGEF(1, c + KS);                           // f(c+KS)      [f2 W8 f2]

    int cb = 0, sb = 2;
    for (; c < NCH; c += KS) {
        asm volatile("s_waitcnt vmcnt(2)" ::: "memory");   // f(c), W(c) landed
        __builtin_amdgcn_s_barrier();            // all waves' f(c) in LDS; buf sb free
        #pragma unroll
        for (int j = 0; j < 8; ++j) wc[j] = wn[j];
        const int cw = (c + KS     < NCH) ? c + KS     : c;
        const int cf = (c + 2 * KS < NCH) ? c + 2 * KS : c;
        WLOADR(wn, cw);
        STAGEF(sb, cf);
        COMPUTE(cb);
        cb = (cb == 2) ? 0 : cb + 1;
        sb = (sb == 2) ? 0 : sb + 1;
    }
    asm volatile("s_waitcnt vmcnt(0)" ::: "memory");       // drain DMA before exit

    #undef COMPUTE
    #undef STAGEF
    #undef WLOADR

    // C/D layout (verified): col = lane&15, row = (lane>>4)*4 + reg
    float* ob = out + o_base + lrow;
    const int r0 = lkb * 4;
    #pragma unroll
    for (int r = 0; r < 4; ++r) {
        atomicAdd(ob + (size_t)(r0 + r) * OUT_DIM,      acc0[r]);
        atomicAdd(ob + (size_t)(16 + r0 + r) * OUT_DIM, acc1[r]);
    }
}

// ------------------------------------------------- fallback (proven v2 path)
__global__ __launch_bounds__(512, 2)
void qgemm_fallback_kernel(const float* __restrict__ x,
                           const float* __restrict__ W,
                           float* __restrict__ out)
{
    __shared__ float xt[B_SZ][512];

    const int tid  = threadIdx.x;
    const int lane = tid & 63;
    const int wave = tid >> 6;
    const int bgrp = wave & 3;
    const int ogrp = wave >> 2;

    const int og  = blockIdx.x & 31;
    const int kgf = blockIdx.x >> 5;

    const int o_base = og * 16 + ogrp * 8;
    const int b_base = bgrp * 8;

    float acc[8][8];
    #pragma unroll
    for (int i = 0; i < 8; ++i)
        #pragma unroll
        for (int o = 0; o < 8; ++o) acc[i][o] = 0.f;

    const int nch = (K_TOTAL + 511) / 512;
    for (int chunk = kgf; chunk < nch; chunk += 16) {
        const int k = chunk * 512 + tid;
        __syncthreads();
        if (k < IN_DIM) {
            #pragma unroll
            for (int b = 0; b < B_SZ; ++b)
                xt[b][tid] = x[b * IN_DIM + k];
        } else {
            const int t = k - IN_DIM;
            double disc = 4198401.0 - 8.0 * (double)t;
            int r = (int)((2049.0 - sqrt(disc)) * 0.5);
            int off = r * IN_DIM - ((r * (r - 1)) >> 1);
            if (t < off) { --r; off = r * IN_DIM - ((r * (r - 1)) >> 1); }
            else if (t >= off + (IN_DIM - r)) { off += IN_DIM - r; ++r; }
            const int ccol = r + (t - off);
            #pragma unroll
            for (int b = 0; b < B_SZ; ++b)
                xt[b][tid] = x[b * IN_DIM + r] * x[b * IN_DIM + ccol];
        }
        __syncthreads();

        const float* wrow = W + (size_t)o_base * K_TOTAL + (size_t)chunk * 512;
        #pragma unroll
        for (int pass = 0; pass < 2; ++pass) {
            const int kk = pass * 256 + lane * 4;
            float4 wv[8];
            #pragma unroll
            for (int o = 0; o < 8; ++o)
                wv[o] = *(const float4*)(wrow + (size_t)o * K_TOTAL + kk);
            float4 xv[8];
            #pragma unroll
            for (int i = 0; i < 8; ++i)
                xv[i] = *(const float4*)&xt[b_base + i][kk];
            #pragma unroll
            for (int o = 0; o < 8; ++o)
                #pragma unroll
                for (int i = 0; i < 8; ++i)
                    acc[i][o] += xv[i].x * wv[o].x + xv[i].y * wv[o].y
                               + xv[i].z * wv[o].z + xv[i].w * wv[o].w;
        }
    }

    #pragma unroll
    for (int i = 0; i < 8; ++i)
        #pragma unroll
        for (int o = 0; o < 8; ++o) {
            float v = acc[i][o];
            #pragma unroll
            for (int m = 1; m < 64; m <<= 1)
                v += __shfl_xor(v, m);
            acc[i][o] = v;
        }

    if (lane == 0) {
        #pragma unroll
        for (int i = 0; i < 8; ++i)
            #pragma unroll
            for (int o = 0; o < 8; ++o)
                atomicAdd(&out[(b_base + i) * OUT_DIM + o_base + o], acc[i][o]);
    }
}

extern "C" void kernel_launch(void* const* d_in, const int* in_sizes, int n_in,
                              void* d_out, int out_size, void* d_ws, size_t ws_size,
                              hipStream_t stream)
{
    const float* x    = (const float*)d_in[0];   // [32,1024] fp32
    const float* W    = (const float*)d_in[1];   // [512, 525824] fp32
    const float* bias = (const float*)d_in[2];   // [512] fp32
    float* out = (float*)d_out;                  // [32,512] fp32

    hipLaunchKernelGGL(bias_init_kernel, dim3(64), dim3(256), 0, stream, bias, out);

    if (ws_size >= NEED_WS) {
        int4* fpk = (int4*)d_ws;
        hipLaunchKernelGGL(feat_pack_kernel, dim3(NCH), dim3(256), 0, stream, x, fpk);
        hipLaunchKernelGGL(qgemm_mfma_kernel, dim3(8 * KS), dim3(256), 0, stream,
                           fpk, W, out);
    } else {
        hipLaunchKernelGGL(qgemm_fallback_kernel, dim3(512), dim3(512), 0, stream,
                           x, W, out);
    }
}